// Round 12
// baseline (1672.460 us; speedup 1.0000x reference)
//
#include <hip/hip_runtime.h>
#include <hip/hip_bf16.h>
#include <stdint.h>
#include <stddef.h>

typedef short bf16x8 __attribute__((ext_vector_type(8)));
typedef float f32x4 __attribute__((ext_vector_type(4)));
typedef int i32x4 __attribute__((ext_vector_type(4)));
typedef unsigned short u16;
typedef unsigned int u32;
typedef unsigned long long u64;

#define SCOPE_AGENT __HIP_MEMORY_SCOPE_AGENT
#define SENT 0xFFFFFFFFFFFFFFFFull

// ---------- helpers: fp32 -> bf16 (RNE) split ----------
__device__ __forceinline__ u16 f2bf(float x) {
  u32 u = __builtin_bit_cast(u32, x);
  u32 r = (u + 0x7fffu + ((u >> 16) & 1u)) >> 16;
  return (u16)r;
}
__device__ __forceinline__ float bf2f(u16 h) {
  u32 u = ((u32)h) << 16;
  return __builtin_bit_cast(float, u);
}
__device__ __forceinline__ void split2(float a, float b, u32& hw, u32& lw) {
  u16 ha = f2bf(a), hb = f2bf(b);
  float ra = a - bf2f(ha), rb = b - bf2f(hb);
  hw = (u32)ha | ((u32)hb << 16);
  lw = (u32)f2bf(ra) | ((u32)f2bf(rb) << 16);
}
// pack h value as (bf16_hi << 16) | bf16_lo (hi never 0xFFFF -> sentinel safe)
__device__ __forceinline__ u32 pack_hl(float v) {
  u16 hi = f2bf(v);
  u16 lo = f2bf(v - bf2f(hi));
  return ((u32)hi << 16) | (u32)lo;
}
__device__ __forceinline__ float tanh_fast(float x) {
  float xc = fminf(9.0f, fmaxf(-9.0f, x));
  float z = exp2f(xc * 2.8853900817779268f);  // e^{2x}
  return (z - 1.0f) * __builtin_amdgcn_rcpf(z + 1.0f);
}

// ---------- prep: transpose + bf16-split a 1024x1024 weight ----------
__global__ void wsplit(const float* __restrict__ W, u16* __restrict__ Thi, u16* __restrict__ Tlo) {
  __shared__ float tile[32][33];
  const int bx = blockIdx.x * 32;  // c base
  const int by = blockIdx.y * 32;  // k base
  const int tx = threadIdx.x, ty = threadIdx.y;  // (32,8)
#pragma unroll
  for (int r = 0; r < 4; ++r) {
    int ky = ty + 8 * r;
    tile[ky][tx] = W[(size_t)(by + ky) * 1024 + bx + tx];
  }
  __syncthreads();
#pragma unroll
  for (int r = 0; r < 4; ++r) {
    int row = ty + 8 * r;           // c-local
    float v = tile[tx][row];        // = W[by+tx][bx+row]
    u16 hi = f2bf(v);
    u16 lo = f2bf(v - bf2f(hi));
    Thi[(size_t)(bx + row) * 1024 + by + tx] = hi;
    Tlo[(size_t)(bx + row) * 1024 + by + tx] = lo;
  }
}

// ---------- prep: ring init ----------
// ring = 4 slots x (16 groups x 2048 u64). Slot 0 <- h0 in 4-row
// block-fragment layout: word (row in [0,4), kp=k/2 in [0,512)) at
//   I4 = (kp>>4)*64 + (kp&3)*16 + ((kp>>2)&3)*4 + row
// i.e. bits: row=I4&3, q=(I4>>2)&3, j2=(I4>>4)&3, hi4=I4>>6,
// kp = hi4*16 + q*4 + j2. Slots 1..3 <- sentinel.
__global__ void hinit(const float* __restrict__ h0, u64* __restrict__ ring) {
  int i = blockIdx.x * 256 + threadIdx.x;  // 0..131071
  int slot = i >> 15, li = i & 32767;
  if (slot == 0) {
    int g = li >> 11, I4 = li & 2047;
    int row = I4 & 3, q = (I4 >> 2) & 3, j2 = (I4 >> 4) & 3, hi4 = I4 >> 6;
    int kp = hi4 * 16 + q * 4 + j2, k = kp * 2;
    int n = g * 4 + row;
    u64 val = (u64)pack_hl(h0[n * 1024 + k]) | ((u64)pack_hl(h0[n * 1024 + k + 1]) << 32);
    __hip_atomic_store(&ring[i], val, __ATOMIC_RELAXED, SCOPE_AGENT);
  } else {
    __hip_atomic_store(&ring[i], SENT, __ATOMIC_RELAXED, SCOPE_AGENT);
  }
}

// ---------- phase 1: xw = x @ Wx + b  (bf16x3 MFMA, 128x128 tile, BK=32) ----------
#define LDT 40  // padded LDS row stride (bf16 elems)

__global__ __launch_bounds__(256, 2) void xw_gemm(
    const float* __restrict__ X, const u16* __restrict__ BThi, const u16* __restrict__ BTlo,
    const float* __restrict__ bias, float* __restrict__ out) {
  __shared__ u16 Ah[128 * LDT], Al[128 * LDT], Bh[128 * LDT], Bl[128 * LDT];
  const int tid = threadIdx.x;
  const int lane = tid & 63, wave = tid >> 6;
  const int wm = wave >> 1, wn = wave & 1;
  const int m0 = blockIdx.y * 128, n0 = blockIdx.x * 128;
  const int arow = tid >> 1, afo = (tid & 1) << 4;
  const int bcol = tid >> 1, bko = (tid & 1) << 4;
  const float* Xa = X + (size_t)(m0 + arow) * 1024 + afo;
  const u16* bhp = BThi + (size_t)(n0 + bcol) * 1024 + bko;
  const u16* blp = BTlo + (size_t)(n0 + bcol) * 1024 + bko;

  f32x4 acc[4][4] = {};

  const int aoff = (wm * 64 + (lane & 15)) * LDT + ((lane >> 4) << 3);
  const int boff = (wn * 64 + (lane & 15)) * LDT + ((lane >> 4) << 3);

  for (int k0 = 0; k0 < 1024; k0 += 32) {
    const float4* xp = (const float4*)(Xa + k0);
    float4 f0 = xp[0], f1 = xp[1], f2 = xp[2], f3 = xp[3];
    i32x4 gbh0 = *(const i32x4*)(bhp + k0);
    i32x4 gbh1 = *(const i32x4*)(bhp + k0 + 8);
    i32x4 gbl0 = *(const i32x4*)(blp + k0);
    i32x4 gbl1 = *(const i32x4*)(blp + k0 + 8);
    u32 hw0, hw1, hw2, hw3, hw4, hw5, hw6, hw7;
    u32 lw0, lw1, lw2, lw3, lw4, lw5, lw6, lw7;
    split2(f0.x, f0.y, hw0, lw0); split2(f0.z, f0.w, hw1, lw1);
    split2(f1.x, f1.y, hw2, lw2); split2(f1.z, f1.w, hw3, lw3);
    split2(f2.x, f2.y, hw4, lw4); split2(f2.z, f2.w, hw5, lw5);
    split2(f3.x, f3.y, hw6, lw6); split2(f3.z, f3.w, hw7, lw7);
    __syncthreads();
    *(i32x4*)&Ah[arow * LDT + afo]     = i32x4{(int)hw0, (int)hw1, (int)hw2, (int)hw3};
    *(i32x4*)&Ah[arow * LDT + afo + 8] = i32x4{(int)hw4, (int)hw5, (int)hw6, (int)hw7};
    *(i32x4*)&Al[arow * LDT + afo]     = i32x4{(int)lw0, (int)lw1, (int)lw2, (int)lw3};
    *(i32x4*)&Al[arow * LDT + afo + 8] = i32x4{(int)lw4, (int)lw5, (int)lw6, (int)lw7};
    *(i32x4*)&Bh[bcol * LDT + bko]     = gbh0;
    *(i32x4*)&Bh[bcol * LDT + bko + 8] = gbh1;
    *(i32x4*)&Bl[bcol * LDT + bko]     = gbl0;
    *(i32x4*)&Bl[bcol * LDT + bko + 8] = gbl1;
    __syncthreads();

    bf16x8 a_h[4], a_l[4], b_h[4], b_l[4];
#pragma unroll
    for (int i = 0; i < 4; ++i) {
      a_h[i] = *(const bf16x8*)(Ah + aoff + i * 16 * LDT);
      a_l[i] = *(const bf16x8*)(Al + aoff + i * 16 * LDT);
      b_h[i] = *(const bf16x8*)(Bh + boff + i * 16 * LDT);
      b_l[i] = *(const bf16x8*)(Bl + boff + i * 16 * LDT);
    }
#pragma unroll
    for (int i = 0; i < 4; ++i)
#pragma unroll
      for (int j = 0; j < 4; ++j)
        acc[i][j] = __builtin_amdgcn_mfma_f32_16x16x32_bf16(a_h[i], b_h[j], acc[i][j], 0, 0, 0);
#pragma unroll
    for (int i = 0; i < 4; ++i)
#pragma unroll
      for (int j = 0; j < 4; ++j)
        acc[i][j] = __builtin_amdgcn_mfma_f32_16x16x32_bf16(a_h[i], b_l[j], acc[i][j], 0, 0, 0);
#pragma unroll
    for (int i = 0; i < 4; ++i)
#pragma unroll
      for (int j = 0; j < 4; ++j)
        acc[i][j] = __builtin_amdgcn_mfma_f32_16x16x32_bf16(a_l[i], b_h[j], acc[i][j], 0, 0, 0);
  }
  const int ccol = n0 + wn * 64 + (lane & 15);
  const int crow = m0 + wm * 64 + ((lane >> 4) << 2);
#pragma unroll
  for (int j = 0; j < 4; ++j) {
    float bv = bias[ccol + j * 16];
#pragma unroll
    for (int i = 0; i < 4; ++i)
#pragma unroll
      for (int r = 0; r < 4; ++r)
        out[(size_t)(crow + i * 16 + r) * 1024 + ccol + j * 16] = acc[i][j][r] + bv;
  }
}

// ---------- phase 2: sequential scan, flagless ring-4, 4-row groups ----------
// 256 WGs x 512 thr. WG (g,cw): rows [4g,4g+4), cols [64cw,64cw+64).
// Wave w owns K-eighth [128w,128w+128); B pinned via inline-asm loads.
// A-row dup x4: lane feeds row = colL&3 (C rows 4..15 ignored). Pull =
// 8 u64/lane with the VERIFIED R11 j2-split: lanes colL<8 own j2 {0,1},
// colL>=8 own {2,3}; the 8-word poll covers EVERY word the wave consumes;
// shfl_xor(lane^8) rebuilds all 4 j2 after convergence. Publish: dense 1KB
// block by tid<128. Ring-4 sentinel/clear protocol unchanged (R8-R11).
#define RST 68  // padded Red row stride (floats)

__global__ __launch_bounds__(512, 2) void rnn_scan(
    const u16* __restrict__ WThi, const u16* __restrict__ WTlo,
    float* __restrict__ out, u64* __restrict__ ring) {
  __shared__ float Red[2][8][4 * RST];
  const int tid = threadIdx.x;
  const int lane = tid & 63, w = tid >> 6;   // w = K-eighth
  const int cw = blockIdx.x & 15, g = blockIdx.x >> 4;  // g in [0,16)
  const int colL = lane & 15, q = lane >> 4;

  // ---- B -> registers/AGPRs via inline asm (never rematerialized) ----
  i32x4 Bh_[4][4], Bl_[4][4];
#pragma unroll
  for (int ct = 0; ct < 4; ++ct) {
    const u16* bhp = WThi + (size_t)(cw * 64 + ct * 16 + colL) * 1024 + w * 128 + (q << 3);
    const u16* blp = WTlo + (size_t)(cw * 64 + ct * 16 + colL) * 1024 + w * 128 + (q << 3);
#pragma unroll
    for (int t = 0; t < 4; ++t) {
      asm volatile("global_load_dwordx4 %0, %1, off" : "=v"(Bh_[ct][t]) : "v"(bhp + t * 32));
      asm volatile("global_load_dwordx4 %0, %1, off" : "=v"(Bl_[ct][t]) : "v"(blp + t * 32));
    }
  }
  asm volatile("s_waitcnt vmcnt(0)" ::: "memory");
  __builtin_amdgcn_sched_barrier(0);

  // final-phase constants (tid<128): dense word pubI = cw*128 + tid.
  // tid bits: row=1:0, q2=3:2, j2b=5:4, b=6 -> kp=(2cw+b)*16+q2*4+j2b,
  // kloc = 2kp-64cw = 32b+8q2+2j2b.
  const int frow = tid & 3;
  const int kloc = 32 * ((tid >> 6) & 1) + 8 * ((tid >> 2) & 3) + 2 * ((tid >> 4) & 3);
  const bool fin = tid < 128;
  const size_t pubI = (size_t)cw * 128 + tid;                  // dense (tid<128)
  const size_t orow = ((size_t)(g * 4 + frow) * 512) * 1024 + cw * 64 + kloc;
  const size_t gslab = (size_t)g * 2048;
  // this lane's 2 owned j2 values: {j2o, j2o+1}
  const int j2o = (colL >> 3) * 2;
  const size_t srcoff = gslab + (size_t)w * 256 + (q << 2) + (colL & 3);

  for (int s = 0; s < 512; ++s) {
    // xw prefetch (cached, WG-private) -- issue before the poll
    const size_t oidx = orow + (size_t)s * 1024;
    float2 xwv = make_float2(0.f, 0.f);
    if (fin) {
      xwv = *(const float2*)&out[oidx];
      asm volatile("" : "+v"(xwv.x), "+v"(xwv.y));
    }

    // poll-pull: 8 owned words; selective re-load of still-sentinel words.
    // __all over the wave verifies every word the wave will consume.
    const u64* src = ring + (size_t)(s & 3) * 32768 + srcoff;
    u64 hv[8];
#pragma unroll
    for (int t = 0; t < 4; ++t)
#pragma unroll
      for (int i = 0; i < 2; ++i)
        hv[t * 2 + i] =
            __hip_atomic_load(src + t * 64 + (j2o + i) * 16, __ATOMIC_RELAXED, SCOPE_AGENT);
    {
      int it = 0;
      while (true) {
        bool d = true;
#pragma unroll
        for (int i = 0; i < 8; ++i) d = d && (hv[i] != SENT);
        if (__all(d) || ++it >= (1 << 16)) break;
#pragma unroll
        for (int t = 0; t < 4; ++t)
#pragma unroll
          for (int i = 0; i < 2; ++i)
            if (hv[t * 2 + i] == SENT)
              hv[t * 2 + i] =
                  __hip_atomic_load(src + t * 64 + (j2o + i) * 16, __ATOMIC_RELAXED, SCOPE_AGENT);
      }
    }

    const bool hi8 = (colL & 8) != 0;
    f32x4 acc[4] = {};
#pragma unroll
    for (int t = 0; t < 4; ++t) {
      // partner exchange: lane^8 holds the other j2 pair for the same (q,row)
      u64 a0 = hv[t * 2 + 0], a1 = hv[t * 2 + 1];
      u64 p0 = __shfl_xor((unsigned long long)a0, 8);
      u64 p1 = __shfl_xor((unsigned long long)a1, 8);
      u64 w0 = hi8 ? p0 : a0;
      u64 w1 = hi8 ? p1 : a1;
      u64 w2 = hi8 ? a0 : p0;
      u64 w3 = hi8 ? a1 : p1;
      i32x4 ahv, alv;
      ahv[0] = (int)__builtin_amdgcn_perm((u32)(w0 >> 32), (u32)w0, 0x07060302u);
      alv[0] = (int)__builtin_amdgcn_perm((u32)(w0 >> 32), (u32)w0, 0x05040100u);
      ahv[1] = (int)__builtin_amdgcn_perm((u32)(w1 >> 32), (u32)w1, 0x07060302u);
      alv[1] = (int)__builtin_amdgcn_perm((u32)(w1 >> 32), (u32)w1, 0x05040100u);
      ahv[2] = (int)__builtin_amdgcn_perm((u32)(w2 >> 32), (u32)w2, 0x07060302u);
      alv[2] = (int)__builtin_amdgcn_perm((u32)(w2 >> 32), (u32)w2, 0x05040100u);
      ahv[3] = (int)__builtin_amdgcn_perm((u32)(w3 >> 32), (u32)w3, 0x07060302u);
      alv[3] = (int)__builtin_amdgcn_perm((u32)(w3 >> 32), (u32)w3, 0x05040100u);
      bf16x8 ah = __builtin_bit_cast(bf16x8, ahv);
      bf16x8 al = __builtin_bit_cast(bf16x8, alv);
#pragma unroll
      for (int ct = 0; ct < 4; ++ct) {
        acc[ct] = __builtin_amdgcn_mfma_f32_16x16x32_bf16(al, __builtin_bit_cast(bf16x8, Bh_[ct][t]), acc[ct], 0, 0, 0);
        acc[ct] = __builtin_amdgcn_mfma_f32_16x16x32_bf16(ah, __builtin_bit_cast(bf16x8, Bl_[ct][t]), acc[ct], 0, 0, 0);
        acc[ct] = __builtin_amdgcn_mfma_f32_16x16x32_bf16(ah, __builtin_bit_cast(bf16x8, Bh_[ct][t]), acc[ct], 0, 0, 0);
      }
    }

    // partials -> LDS: only C rows 0-3 are real (q==0 lanes)
    if (q == 0) {
#pragma unroll
      for (int ct = 0; ct < 4; ++ct)
#pragma unroll
        for (int r = 0; r < 4; ++r)
          Red[s & 1][w][r * RST + ct * 16 + colL] = acc[ct][r];
    }
    __syncthreads();

    if (fin) {
      // final: reduce 8 K-partials for outputs (frow, kloc), (frow, kloc+1)
      float s0 = xwv.x, s1 = xwv.y;
#pragma unroll
      for (int ww = 0; ww < 8; ++ww) {
        float2 pr = *(const float2*)&Red[s & 1][ww][frow * RST + kloc];
        s0 += pr.x; s1 += pr.y;
      }
      float h0v = tanh_fast(s0), h1v = tanh_fast(s1);

      // publish h_{s+1} into ring[(s+1)&3]: dense 1KB block per WG
      u64 val = (u64)pack_hl(h0v) | ((u64)pack_hl(h1v) << 32);
      __hip_atomic_store(ring + (size_t)((s + 1) & 3) * 32768 + gslab + pubI, val,
                         __ATOMIC_RELAXED, SCOPE_AGENT);
      // sentinel my word in the slot read last step (same thread republishes
      // this word at s+2; in-order vmcnt retirement at the step-(s+1) pull
      // guarantees the clear is globally visible a full step before reuse)
      if (s > 0)
        __hip_atomic_store(ring + (size_t)((s - 1) & 3) * 32768 + gslab + pubI, SENT,
                           __ATOMIC_RELAXED, SCOPE_AGENT);
      *(float2*)&out[oidx] = make_float2(h0v, h1v);
    }
  }
}

// ---------- launch ----------
extern "C" void kernel_launch(void* const* d_in, const int* in_sizes, int n_in,
                              void* d_out, int out_size, void* d_ws, size_t ws_size,
                              hipStream_t stream) {
  const float* x    = (const float*)d_in[0];
  const float* h0   = (const float*)d_in[1];
  const float* Wx   = (const float*)d_in[2];
  const float* Wh   = (const float*)d_in[3];
  const float* bias = (const float*)d_in[4];
  float* out = (float*)d_out;
  char* ws = (char*)d_ws;

  const size_t MB2 = (size_t)1 << 21;
  u16* WxThi = (u16*)(ws);
  u16* WxTlo = (u16*)(ws + MB2);
  u16* WhThi = (u16*)(ws + 2 * MB2);
  u16* WhTlo = (u16*)(ws + 3 * MB2);
  u64* ring  = (u64*)(ws + 4 * MB2);  // 4 slots x 32768 u64 = 1 MB

  wsplit<<<dim3(32, 32), dim3(32, 8), 0, stream>>>(Wx, WxThi, WxTlo);
  wsplit<<<dim3(32, 32), dim3(32, 8), 0, stream>>>(Wh, WhThi, WhTlo);
  hinit<<<512, 256, 0, stream>>>(h0, ring);
  xw_gemm<<<dim3(8, 256), 256, 0, stream>>>(x, WxThi, WxTlo, bias, out);
  rnn_scan<<<256, 512, 0, stream>>>(WhThi, WhTlo, out, ring);
}

// Round 13
// 1578.644 us; speedup vs baseline: 1.0594x; 1.0594x over previous
//
#include <hip/hip_runtime.h>
#include <hip/hip_bf16.h>
#include <stdint.h>
#include <stddef.h>

typedef short bf16x8 __attribute__((ext_vector_type(8)));
typedef float f32x4 __attribute__((ext_vector_type(4)));
typedef int i32x4 __attribute__((ext_vector_type(4)));
typedef unsigned short u16;
typedef unsigned int u32;
typedef unsigned long long u64;

#define SCOPE_AGENT __HIP_MEMORY_SCOPE_AGENT
#define SENT 0xFFFFFFFFFFFFFFFFull

// ---------- helpers: fp32 -> bf16 (RNE) split ----------
__device__ __forceinline__ u16 f2bf(float x) {
  u32 u = __builtin_bit_cast(u32, x);
  u32 r = (u + 0x7fffu + ((u >> 16) & 1u)) >> 16;
  return (u16)r;
}
__device__ __forceinline__ float bf2f(u16 h) {
  u32 u = ((u32)h) << 16;
  return __builtin_bit_cast(float, u);
}
__device__ __forceinline__ void split2(float a, float b, u32& hw, u32& lw) {
  u16 ha = f2bf(a), hb = f2bf(b);
  float ra = a - bf2f(ha), rb = b - bf2f(hb);
  hw = (u32)ha | ((u32)hb << 16);
  lw = (u32)f2bf(ra) | ((u32)f2bf(rb) << 16);
}
// pack h value as (bf16_hi << 16) | bf16_lo (hi never 0xFFFF -> sentinel safe)
__device__ __forceinline__ u32 pack_hl(float v) {
  u16 hi = f2bf(v);
  u16 lo = f2bf(v - bf2f(hi));
  return ((u32)hi << 16) | (u32)lo;
}
__device__ __forceinline__ float tanh_fast(float x) {
  float xc = fminf(9.0f, fmaxf(-9.0f, x));
  float z = exp2f(xc * 2.8853900817779268f);  // e^{2x}
  return (z - 1.0f) * __builtin_amdgcn_rcpf(z + 1.0f);
}

// ---------- prep: transpose + bf16-split a 1024x1024 weight ----------
__global__ void wsplit(const float* __restrict__ W, u16* __restrict__ Thi, u16* __restrict__ Tlo) {
  __shared__ float tile[32][33];
  const int bx = blockIdx.x * 32;  // c base
  const int by = blockIdx.y * 32;  // k base
  const int tx = threadIdx.x, ty = threadIdx.y;  // (32,8)
#pragma unroll
  for (int r = 0; r < 4; ++r) {
    int ky = ty + 8 * r;
    tile[ky][tx] = W[(size_t)(by + ky) * 1024 + bx + tx];
  }
  __syncthreads();
#pragma unroll
  for (int r = 0; r < 4; ++r) {
    int row = ty + 8 * r;           // c-local
    float v = tile[tx][row];        // = W[by+tx][bx+row]
    u16 hi = f2bf(v);
    u16 lo = f2bf(v - bf2f(hi));
    Thi[(size_t)(bx + row) * 1024 + by + tx] = hi;
    Tlo[(size_t)(bx + row) * 1024 + by + tx] = lo;
  }
}

// ---------- prep: ring init ----------
// ring = 4 slots x (8 groups x 4096 u64). Slot 0 <- h0 in 8-row block-fragment
// layout: word (row in [0,8), kp=k/2 in [0,512)) at
//   I8 = (kp>>4)*128 + (kp&3)*32 + ((kp>>2)&3)*8 + row
// with kp = hi4*16 + q*4 + j2 (hi4=I8>>7, j2=(I8>>5)&3, q=(I8>>3)&3, row=I8&7).
// Slots 1..3 <- sentinel.
__global__ void hinit(const float* __restrict__ h0, u64* __restrict__ ring) {
  int i = blockIdx.x * 256 + threadIdx.x;  // 0..131071
  int slot = i >> 15, li = i & 32767;
  if (slot == 0) {
    int g = li >> 12, I8 = li & 4095;
    int row = I8 & 7, q = (I8 >> 3) & 3, j2 = (I8 >> 5) & 3, hi4 = I8 >> 7;
    int kp = hi4 * 16 + q * 4 + j2, k = kp * 2;
    int n = g * 8 + row;
    u64 val = (u64)pack_hl(h0[n * 1024 + k]) | ((u64)pack_hl(h0[n * 1024 + k + 1]) << 32);
    __hip_atomic_store(&ring[i], val, __ATOMIC_RELAXED, SCOPE_AGENT);
  } else {
    __hip_atomic_store(&ring[i], SENT, __ATOMIC_RELAXED, SCOPE_AGENT);
  }
}

// ---------- phase 1: xw = x @ Wx + b  (bf16x3 MFMA, 128x128 tile, BK=32) ----------
#define LDT 40  // padded LDS row stride (bf16 elems)

__global__ __launch_bounds__(256, 2) void xw_gemm(
    const float* __restrict__ X, const u16* __restrict__ BThi, const u16* __restrict__ BTlo,
    const float* __restrict__ bias, float* __restrict__ out) {
  __shared__ u16 Ah[128 * LDT], Al[128 * LDT], Bh[128 * LDT], Bl[128 * LDT];
  const int tid = threadIdx.x;
  const int lane = tid & 63, wave = tid >> 6;
  const int wm = wave >> 1, wn = wave & 1;
  const int m0 = blockIdx.y * 128, n0 = blockIdx.x * 128;
  const int arow = tid >> 1, afo = (tid & 1) << 4;
  const int bcol = tid >> 1, bko = (tid & 1) << 4;
  const float* Xa = X + (size_t)(m0 + arow) * 1024 + afo;
  const u16* bhp = BThi + (size_t)(n0 + bcol) * 1024 + bko;
  const u16* blp = BTlo + (size_t)(n0 + bcol) * 1024 + bko;

  f32x4 acc[4][4] = {};

  const int aoff = (wm * 64 + (lane & 15)) * LDT + ((lane >> 4) << 3);
  const int boff = (wn * 64 + (lane & 15)) * LDT + ((lane >> 4) << 3);

  for (int k0 = 0; k0 < 1024; k0 += 32) {
    const float4* xp = (const float4*)(Xa + k0);
    float4 f0 = xp[0], f1 = xp[1], f2 = xp[2], f3 = xp[3];
    i32x4 gbh0 = *(const i32x4*)(bhp + k0);
    i32x4 gbh1 = *(const i32x4*)(bhp + k0 + 8);
    i32x4 gbl0 = *(const i32x4*)(blp + k0);
    i32x4 gbl1 = *(const i32x4*)(blp + k0 + 8);
    u32 hw0, hw1, hw2, hw3, hw4, hw5, hw6, hw7;
    u32 lw0, lw1, lw2, lw3, lw4, lw5, lw6, lw7;
    split2(f0.x, f0.y, hw0, lw0); split2(f0.z, f0.w, hw1, lw1);
    split2(f1.x, f1.y, hw2, lw2); split2(f1.z, f1.w, hw3, lw3);
    split2(f2.x, f2.y, hw4, lw4); split2(f2.z, f2.w, hw5, lw5);
    split2(f3.x, f3.y, hw6, lw6); split2(f3.z, f3.w, hw7, lw7);
    __syncthreads();
    *(i32x4*)&Ah[arow * LDT + afo]     = i32x4{(int)hw0, (int)hw1, (int)hw2, (int)hw3};
    *(i32x4*)&Ah[arow * LDT + afo + 8] = i32x4{(int)hw4, (int)hw5, (int)hw6, (int)hw7};
    *(i32x4*)&Al[arow * LDT + afo]     = i32x4{(int)lw0, (int)lw1, (int)lw2, (int)lw3};
    *(i32x4*)&Al[arow * LDT + afo + 8] = i32x4{(int)lw4, (int)lw5, (int)lw6, (int)lw7};
    *(i32x4*)&Bh[bcol * LDT + bko]     = gbh0;
    *(i32x4*)&Bh[bcol * LDT + bko + 8] = gbh1;
    *(i32x4*)&Bl[bcol * LDT + bko]     = gbl0;
    *(i32x4*)&Bl[bcol * LDT + bko + 8] = gbl1;
    __syncthreads();

    bf16x8 a_h[4], a_l[4], b_h[4], b_l[4];
#pragma unroll
    for (int i = 0; i < 4; ++i) {
      a_h[i] = *(const bf16x8*)(Ah + aoff + i * 16 * LDT);
      a_l[i] = *(const bf16x8*)(Al + aoff + i * 16 * LDT);
      b_h[i] = *(const bf16x8*)(Bh + boff + i * 16 * LDT);
      b_l[i] = *(const bf16x8*)(Bl + boff + i * 16 * LDT);
    }
#pragma unroll
    for (int i = 0; i < 4; ++i)
#pragma unroll
      for (int j = 0; j < 4; ++j)
        acc[i][j] = __builtin_amdgcn_mfma_f32_16x16x32_bf16(a_h[i], b_h[j], acc[i][j], 0, 0, 0);
#pragma unroll
    for (int i = 0; i < 4; ++i)
#pragma unroll
      for (int j = 0; j < 4; ++j)
        acc[i][j] = __builtin_amdgcn_mfma_f32_16x16x32_bf16(a_h[i], b_l[j], acc[i][j], 0, 0, 0);
#pragma unroll
    for (int i = 0; i < 4; ++i)
#pragma unroll
      for (int j = 0; j < 4; ++j)
        acc[i][j] = __builtin_amdgcn_mfma_f32_16x16x32_bf16(a_l[i], b_h[j], acc[i][j], 0, 0, 0);
  }
  const int ccol = n0 + wn * 64 + (lane & 15);
  const int crow = m0 + wm * 64 + ((lane >> 4) << 2);
#pragma unroll
  for (int j = 0; j < 4; ++j) {
    float bv = bias[ccol + j * 16];
#pragma unroll
    for (int i = 0; i < 4; ++i)
#pragma unroll
      for (int r = 0; r < 4; ++r)
        out[(size_t)(crow + i * 16 + r) * 1024 + ccol + j * 16] = acc[i][j][r] + bv;
  }
}

// ---------- phase 2: sequential scan, flagless ring-4, 8-row groups ----------
// 128 WGs x 512 thr. WG (g,cw): rows [8g,8g+8), cols [64cw,64cw+64).
// Wave w owns K-eighth [128w,128w+128); B pinned via inline-asm loads.
// Pull = 8 u64/lane: lanes colL<8 load j2 in {0,1}, colL>=8 load j2 in {2,3}
// for the SAME (q,row=colL&7) words; the 8-word poll therefore covers EVERY
// word the wave consumes. After the poll converges, shfl_xor(lane^8)
// rebuilds all 4 j2 per lane. Publish: dense 2KB block by tid<256.
// Ring-4 sentinel/clear protocol as R8-R11.
#define RST 68  // padded Red row stride (floats)

__global__ __launch_bounds__(512, 2) void rnn_scan(
    const u16* __restrict__ WThi, const u16* __restrict__ WTlo,
    float* __restrict__ out, u64* __restrict__ ring) {
  __shared__ float Red[2][8][8 * RST];
  const int tid = threadIdx.x;
  const int lane = tid & 63, w = tid >> 6;   // w = K-eighth
  const int cw = blockIdx.x & 15, g = blockIdx.x >> 4;
  const int colL = lane & 15, q = lane >> 4;

  // ---- B -> registers/AGPRs via inline asm (never rematerialized) ----
  i32x4 Bh_[4][4], Bl_[4][4];
#pragma unroll
  for (int ct = 0; ct < 4; ++ct) {
    const u16* bhp = WThi + (size_t)(cw * 64 + ct * 16 + colL) * 1024 + w * 128 + (q << 3);
    const u16* blp = WTlo + (size_t)(cw * 64 + ct * 16 + colL) * 1024 + w * 128 + (q << 3);
#pragma unroll
    for (int t = 0; t < 4; ++t) {
      asm volatile("global_load_dwordx4 %0, %1, off" : "=v"(Bh_[ct][t]) : "v"(bhp + t * 32));
      asm volatile("global_load_dwordx4 %0, %1, off" : "=v"(Bl_[ct][t]) : "v"(blp + t * 32));
    }
  }
  asm volatile("s_waitcnt vmcnt(0)" ::: "memory");
  __builtin_amdgcn_sched_barrier(0);

  // final-phase constants (tid<256): dense word pubI = cw*256 + tid.
  // tid bits: row=2:0, q2=4:3, j2b=6:5, b=7 -> kp=(2cw+b)*16+q2*4+j2b,
  // kloc = 2kp-64cw = 32b+8q2+2j2b (always < 64 for tid<256).
  const int frow = tid & 7;
  const int kloc = 32 * (tid >> 7) + 8 * ((tid >> 3) & 3) + 2 * ((tid >> 5) & 3);
  const bool fin = tid < 256;
  const size_t pubI = (size_t)cw * 256 + tid;                  // dense (tid<256)
  const size_t orow = ((size_t)(g * 8 + frow) * 512) * 1024 + cw * 64 + kloc;
  const size_t gslab = (size_t)g * 4096;
  // this lane's 2 owned j2 values: {j2o, j2o+1}
  const int j2o = (colL >> 3) * 2;
  const size_t srcoff = gslab + (size_t)w * 512 + (q << 3) + (colL & 7);

  for (int s = 0; s < 512; ++s) {
    // xw prefetch (cached, WG-private) -- issue before the poll
    const size_t oidx = orow + (size_t)s * 1024;
    float2 xwv = make_float2(0.f, 0.f);
    if (fin) {
      xwv = *(const float2*)&out[oidx];
      asm volatile("" : "+v"(xwv.x), "+v"(xwv.y));
    }

    // poll-pull: 8 owned words; selective re-load of still-sentinel words.
    // __all over the wave verifies every word the wave will consume.
    const u64* src = ring + (size_t)(s & 3) * 32768 + srcoff;
    u64 hv[8];
#pragma unroll
    for (int t = 0; t < 4; ++t)
#pragma unroll
      for (int i = 0; i < 2; ++i)
        hv[t * 2 + i] =
            __hip_atomic_load(src + t * 128 + (j2o + i) * 32, __ATOMIC_RELAXED, SCOPE_AGENT);
    {
      int it = 0;
      while (true) {
        bool d = true;
#pragma unroll
        for (int i = 0; i < 8; ++i) d = d && (hv[i] != SENT);
        if (__all(d) || ++it >= (1 << 16)) break;
#pragma unroll
        for (int t = 0; t < 4; ++t)
#pragma unroll
          for (int i = 0; i < 2; ++i)
            if (hv[t * 2 + i] == SENT)
              hv[t * 2 + i] =
                  __hip_atomic_load(src + t * 128 + (j2o + i) * 32, __ATOMIC_RELAXED, SCOPE_AGENT);
      }
    }

    const bool hi8 = (colL & 8) != 0;
    f32x4 acc[4] = {};
#pragma unroll
    for (int t = 0; t < 4; ++t) {
      // partner exchange: lane^8 holds the other j2 pair for the same (q,row)
      u64 a0 = hv[t * 2 + 0], a1 = hv[t * 2 + 1];
      u64 p0 = __shfl_xor((unsigned long long)a0, 8);
      u64 p1 = __shfl_xor((unsigned long long)a1, 8);
      u64 w0 = hi8 ? p0 : a0;
      u64 w1 = hi8 ? p1 : a1;
      u64 w2 = hi8 ? a0 : p0;
      u64 w3 = hi8 ? a1 : p1;
      i32x4 ahv, alv;
      ahv[0] = (int)__builtin_amdgcn_perm((u32)(w0 >> 32), (u32)w0, 0x07060302u);
      alv[0] = (int)__builtin_amdgcn_perm((u32)(w0 >> 32), (u32)w0, 0x05040100u);
      ahv[1] = (int)__builtin_amdgcn_perm((u32)(w1 >> 32), (u32)w1, 0x07060302u);
      alv[1] = (int)__builtin_amdgcn_perm((u32)(w1 >> 32), (u32)w1, 0x05040100u);
      ahv[2] = (int)__builtin_amdgcn_perm((u32)(w2 >> 32), (u32)w2, 0x07060302u);
      alv[2] = (int)__builtin_amdgcn_perm((u32)(w2 >> 32), (u32)w2, 0x05040100u);
      ahv[3] = (int)__builtin_amdgcn_perm((u32)(w3 >> 32), (u32)w3, 0x07060302u);
      alv[3] = (int)__builtin_amdgcn_perm((u32)(w3 >> 32), (u32)w3, 0x05040100u);
      bf16x8 ah = __builtin_bit_cast(bf16x8, ahv);
      bf16x8 al = __builtin_bit_cast(bf16x8, alv);
#pragma unroll
      for (int ct = 0; ct < 4; ++ct) {
        acc[ct] = __builtin_amdgcn_mfma_f32_16x16x32_bf16(al, __builtin_bit_cast(bf16x8, Bh_[ct][t]), acc[ct], 0, 0, 0);
        acc[ct] = __builtin_amdgcn_mfma_f32_16x16x32_bf16(ah, __builtin_bit_cast(bf16x8, Bl_[ct][t]), acc[ct], 0, 0, 0);
        acc[ct] = __builtin_amdgcn_mfma_f32_16x16x32_bf16(ah, __builtin_bit_cast(bf16x8, Bh_[ct][t]), acc[ct], 0, 0, 0);
      }
    }

    // partials -> LDS: C rows 8-15 duplicate rows 0-7 (A-row dup), store q<2
    if (q < 2) {
#pragma unroll
      for (int ct = 0; ct < 4; ++ct)
#pragma unroll
        for (int r = 0; r < 4; ++r)
          Red[s & 1][w][(q * 4 + r) * RST + ct * 16 + colL] = acc[ct][r];
    }
    __syncthreads();

    if (fin) {
      // final: reduce 8 K-partials for outputs (frow, kloc), (frow, kloc+1)
      float s0 = xwv.x, s1 = xwv.y;
#pragma unroll
      for (int ww = 0; ww < 8; ++ww) {
        float2 pr = *(const float2*)&Red[s & 1][ww][frow * RST + kloc];
        s0 += pr.x; s1 += pr.y;
      }
      float h0v = tanh_fast(s0), h1v = tanh_fast(s1);

      // publish h_{s+1} into ring[(s+1)&3]: dense 2KB block per WG
      u64 val = (u64)pack_hl(h0v) | ((u64)pack_hl(h1v) << 32);
      __hip_atomic_store(ring + (size_t)((s + 1) & 3) * 32768 + gslab + pubI, val,
                         __ATOMIC_RELAXED, SCOPE_AGENT);
      // sentinel my word in the slot read last step (same thread republishes
      // this word at s+2; in-order vmcnt retirement at the step-(s+1) pull
      // guarantees the clear is globally visible a full step before reuse)
      if (s > 0)
        __hip_atomic_store(ring + (size_t)((s - 1) & 3) * 32768 + gslab + pubI, SENT,
                           __ATOMIC_RELAXED, SCOPE_AGENT);
      *(float2*)&out[oidx] = make_float2(h0v, h1v);
    }
  }
}

// ---------- launch ----------
extern "C" void kernel_launch(void* const* d_in, const int* in_sizes, int n_in,
                              void* d_out, int out_size, void* d_ws, size_t ws_size,
                              hipStream_t stream) {
  const float* x    = (const float*)d_in[0];
  const float* h0   = (const float*)d_in[1];
  const float* Wx   = (const float*)d_in[2];
  const float* Wh   = (const float*)d_in[3];
  const float* bias = (const float*)d_in[4];
  float* out = (float*)d_out;
  char* ws = (char*)d_ws;

  const size_t MB2 = (size_t)1 << 21;
  u16* WxThi = (u16*)(ws);
  u16* WxTlo = (u16*)(ws + MB2);
  u16* WhThi = (u16*)(ws + 2 * MB2);
  u16* WhTlo = (u16*)(ws + 3 * MB2);
  u64* ring  = (u64*)(ws + 4 * MB2);  // 4 slots x 32768 u64 = 1 MB

  wsplit<<<dim3(32, 32), dim3(32, 8), 0, stream>>>(Wx, WxThi, WxTlo);
  wsplit<<<dim3(32, 32), dim3(32, 8), 0, stream>>>(Wh, WhThi, WhTlo);
  hinit<<<512, 256, 0, stream>>>(h0, ring);
  xw_gemm<<<dim3(8, 256), 256, 0, stream>>>(x, WxThi, WxTlo, bias, out);
  rnn_scan<<<128, 512, 0, stream>>>(WhThi, WhTlo, out, ring);
}